// Round 11
// baseline (183.622 us; speedup 1.0000x reference)
//
#include <hip/hip_runtime.h>

#define NPTS 131072
#define NE 8
#define DIN 90
#define NH 256

typedef __attribute__((ext_vector_type(8))) short bf16x8;
typedef __attribute__((ext_vector_type(4))) float f32x4;
typedef __attribute__((ext_vector_type(2))) float f32x2;
typedef __attribute__((ext_vector_type(4))) unsigned int u32x4;
typedef __attribute__((ext_vector_type(2))) unsigned int u32x2;
typedef __attribute__((ext_vector_type(4), aligned(4))) float f32x4a;
typedef __attribute__((ext_vector_type(2), aligned(4))) float f32x2a;

__device__ __forceinline__ unsigned short f2bf(float f) {
  unsigned int u = __float_as_uint(f);
  u += 0x7fffu + ((u >> 16) & 1u);
  return (unsigned short)(u >> 16);
}

#if defined(__has_builtin) && __has_builtin(__builtin_amdgcn_cvt_pk_bf16_f32)
typedef __attribute__((ext_vector_type(2))) __bf16 bf16x2;
__device__ __forceinline__ unsigned int pkbf(float f0, float f1) {
  bf16x2 r = __builtin_amdgcn_cvt_pk_bf16_f32(f0, f1);
  return __builtin_bit_cast(unsigned int, r);
}
#else
__device__ __forceinline__ unsigned int pkbf(float f0, float f1) {
  unsigned int u0 = __float_as_uint(f0) + 0x7fffu;
  unsigned int u1 = __float_as_uint(f1) + 0x7fffu;
  return __builtin_amdgcn_perm(u1, u0, 0x07060302u);
}
#endif

__device__ __forceinline__ bf16x8 cvt8(f32x4 a, f32x4 b) {
  u32x4 r;
  r[0] = pkbf(a[0], a[1]);
  r[1] = pkbf(a[2], a[3]);
  r[2] = pkbf(b[0], b[1]);
  r[3] = pkbf(b[2], b[3]);
  return __builtin_bit_cast(bf16x8, r);
}

// Coalesced prep (R9-proven, ~4us). Blocks 0..31: W1, 32..39: W2.
__global__ __launch_bounds__(256) void prep(const float* __restrict__ W1,
                                            const float* __restrict__ W2,
                                            unsigned short* __restrict__ W1T,
                                            unsigned short* __restrict__ W2T) {
  const int t = threadIdx.x;
  if (blockIdx.x < 32) {
    const int e = blockIdx.x >> 2;
    const int n0 = (blockIdx.x & 3) * 64;
    __shared__ unsigned int ld[64][49];  // stride 49: conflict-free transpose
    const int nl = t & 63;
    const int kq = t >> 6;
#pragma unroll
    for (int j = 0; j < 12; ++j) {
      const int kp2 = kq + 4 * j;
      const int k0 = 2 * kp2, k1 = k0 + 1;
      unsigned int lo = 0, hi = 0;
      if (k0 < DIN) lo = f2bf(W1[((size_t)e * DIN + k0) * NH + n0 + nl]);
      if (k1 < DIN) hi = f2bf(W1[((size_t)e * DIN + k1) * NH + n0 + nl]);
      ld[nl][kp2] = lo | (hi << 16);
    }
    __syncthreads();
    unsigned int* dst = (unsigned int*)(W1T + (size_t)(e * NH + n0) * 96);
#pragma unroll
    for (int j = 0; j < 12; ++j) {
      const int u = t + 256 * j;
      dst[u] = ld[u / 48][u % 48];
    }
  } else {
    const int e = blockIdx.x - 32;
    unsigned int* dst = (unsigned int*)W2T + (size_t)e * 2048;
    const float* src = W2 + (size_t)e * 1024;
#pragma unroll
    for (int j = 0; j < 8; ++j) {
      const int u = t + 256 * j;
      const int o = u >> 7;
      const int kp = u & 127;
      unsigned int v = 0;
      if (o < 4) {
        unsigned int lo = f2bf(src[(2 * kp) * 4 + o]);
        unsigned int hi = f2bf(src[(2 * kp + 1) * 4 + o]);
        v = lo | (hi << 16);
      }
      dst[u] = v;
    }
  }
}

#define UNRL _Pragma("unroll")

// feat frag (ks, nf) for lane (l15,l4): unit index (ks*4+l4)*64 + 16*nf + l15.
// 16 lanes (l15) read 256B contiguous -> conflict-free.
#define FEAT(KS, NF) \
  (*(const bf16x8*)&sFeat[(((KS)*4 + l4) * 64 + 16 * (NF) + l15) * 8])

#define MF(W_, F_, C_) __builtin_amdgcn_mfma_f32_16x16x32_bf16(W_, F_, C_, 0, 0, 0)

#define LOADW1MF0(E_, C_, D0, D1, D2)                                           \
  do {                                                                          \
    const unsigned short* _p =                                                  \
        W1T + (size_t)((E_) * NH + 128 * (C_) + 32 * wid + l15) * 96 + 8 * l4;  \
    D0 = *(const bf16x8*)(_p);                                                  \
    D1 = *(const bf16x8*)(_p + 32);                                             \
    D2 = *(const bf16x8*)(_p + 64);                                             \
  } while (0)

#define LOADW1MF1(E_, C_)                                                       \
  do {                                                                          \
    const unsigned short* _p = W1T +                                            \
        (size_t)((E_) * NH + 128 * (C_) + 32 * wid + 16 + l15) * 96 + 8 * l4;   \
    w1m1_0 = *(const bf16x8*)(_p);                                              \
    w1m1_1 = *(const bf16x8*)(_p + 32);                                         \
    w1m1_2 = *(const bf16x8*)(_p + 64);                                         \
  } while (0)

#define LOADBW(E_, C_)                                                          \
  do {                                                                          \
    bw = *(const bf16x8*)(W2T + (size_t)((E_) * 16 + l15) * NH + 128 * (C_) +   \
                          32 * wid + 8 * l4);                                   \
  } while (0)

#define EPI(MF_)                                                                \
  UNRL for (int nf = 0; nf < 4; ++nf) {                                         \
    const float _w = wv[nf];                                                    \
    f32x4 _a = acc[nf];                                                         \
    f32x2 _p0, _p1;                                                             \
    _p0[0] = _a[0]; _p0[1] = _a[1];                                             \
    _p1[0] = _a[2]; _p1[1] = _a[3];                                             \
    const f32x2 _z = {0.f, 0.f};                                                \
    _p0 = __builtin_elementwise_max(_p0, _z) * _w;                              \
    _p1 = __builtin_elementwise_max(_p1, _z) * _w;                              \
    u32x2 _pk;                                                                  \
    _pk[0] = pkbf(_p0[0], _p0[1]);                                              \
    _pk[1] = pkbf(_p1[0], _p1[1]);                                              \
    *(u32x2*)&sH[gbase + (nf * 64 + (l15 + 16 * (2 * (MF_) + (l4 >> 1)))) * 8 + \
                 4 * (l4 & 1)] = _pk;                                           \
  }

// One (e,c) step. Slim buffers: mf0 W1 double-buffered (CM*/NM*), mf1 W1 +
// bw single-buffered (loaded this iter; consumed 12 / 24 MFMAs later ->
// L2 latency covered). Feat frags streamed from LDS per-ks (16 transient
// regs vs R9's 48 persistent). asm memory barrier after EPI(0) prevents the
// compiler CSE-ing the 12 feat frags across mf0/mf1 (which would re-inflate
// live regs past the 128 cap and spill).
#define STEPD(E_, C_, LDWV_, EN_, CN_, CM0, CM1, CM2, NM0, NM1, NM2)            \
  do {                                                                          \
    const int _cb = 128 * (C_) + 32 * wid;                                      \
    f32x4 _b1v0 = *(const f32x4*)&sB1[(E_) * NH + _cb + 4 * l4];                \
    f32x4 _b1v1 = *(const f32x4*)&sB1[(E_) * NH + _cb + 16 + 4 * l4];           \
    if (LDWV_) {                                                                \
      UNRL for (int nf = 0; nf < 4; ++nf) wv[nf] = sW[(E_)][16 * nf + l15];     \
    }                                                                           \
    LOADW1MF1(E_, C_);                                                          \
    LOADBW(E_, C_);                                                             \
    LOADW1MF0(EN_, CN_, NM0, NM1, NM2);                                         \
    {                                                                           \
      f32x4 acc[4];                                                             \
      bf16x8 _f0, _f1, _f2, _f3;                                                \
      __builtin_amdgcn_s_setprio(1);                                            \
      _f0 = FEAT(0, 0); _f1 = FEAT(0, 1); _f2 = FEAT(0, 2); _f3 = FEAT(0, 3);   \
      acc[0] = MF(CM0, _f0, _b1v0); acc[1] = MF(CM0, _f1, _b1v0);               \
      acc[2] = MF(CM0, _f2, _b1v0); acc[3] = MF(CM0, _f3, _b1v0);               \
      _f0 = FEAT(1, 0); _f1 = FEAT(1, 1); _f2 = FEAT(1, 2); _f3 = FEAT(1, 3);   \
      acc[0] = MF(CM1, _f0, acc[0]); acc[1] = MF(CM1, _f1, acc[1]);             \
      acc[2] = MF(CM1, _f2, acc[2]); acc[3] = MF(CM1, _f3, acc[3]);             \
      _f0 = FEAT(2, 0); _f1 = FEAT(2, 1); _f2 = FEAT(2, 2); _f3 = FEAT(2, 3);   \
      acc[0] = MF(CM2, _f0, acc[0]); acc[1] = MF(CM2, _f1, acc[1]);             \
      acc[2] = MF(CM2, _f2, acc[2]); acc[3] = MF(CM2, _f3, acc[3]);             \
      __builtin_amdgcn_s_setprio(0);                                            \
      EPI(0)                                                                    \
      asm volatile("" ::: "memory");  /* force feat re-read, cap live regs */   \
      __builtin_amdgcn_s_setprio(1);                                            \
      _f0 = FEAT(0, 0); _f1 = FEAT(0, 1); _f2 = FEAT(0, 2); _f3 = FEAT(0, 3);   \
      acc[0] = MF(w1m1_0, _f0, _b1v1); acc[1] = MF(w1m1_0, _f1, _b1v1);         \
      acc[2] = MF(w1m1_0, _f2, _b1v1); acc[3] = MF(w1m1_0, _f3, _b1v1);         \
      _f0 = FEAT(1, 0); _f1 = FEAT(1, 1); _f2 = FEAT(1, 2); _f3 = FEAT(1, 3);   \
      acc[0] = MF(w1m1_1, _f0, acc[0]); acc[1] = MF(w1m1_1, _f1, acc[1]);       \
      acc[2] = MF(w1m1_1, _f2, acc[2]); acc[3] = MF(w1m1_1, _f3, acc[3]);       \
      _f0 = FEAT(2, 0); _f1 = FEAT(2, 1); _f2 = FEAT(2, 2); _f3 = FEAT(2, 3);   \
      acc[0] = MF(w1m1_2, _f0, acc[0]); acc[1] = MF(w1m1_2, _f1, acc[1]);       \
      acc[2] = MF(w1m1_2, _f2, acc[2]); acc[3] = MF(w1m1_2, _f3, acc[3]);       \
      __builtin_amdgcn_s_setprio(0);                                            \
      EPI(1)                                                                    \
    }                                                                           \
    __builtin_amdgcn_s_setprio(1);                                              \
    UNRL for (int rf = 0; rf < 4; ++rf) {                                       \
      bf16x8 _ah = *(const bf16x8*)&sH[gbase + (rf * 64 + lane) * 8];           \
      facc[rf] = __builtin_amdgcn_mfma_f32_16x16x32_bf16(_ah, bw, facc[rf],     \
                                                         0, 0, 0);              \
    }                                                                           \
    __builtin_amdgcn_s_setprio(0);                                              \
  } while (0)

// R17: dense main, feat in LDS. bfr (48 VGPR, identical across all 4 waves,
// loop-invariant) moves to one shared 12288B LDS copy; mf1-W1 + bw drop to
// single-buffer. Demand est ~94 arch + 32 acc = ~126 unified -> (256,4)'s
// 128 cap holds WITHOUT spills (R8's spill was demand ~158 vs 128) ->
// 4 waves/SIMD, 4 blocks/CU (LDS 39936B x4 = 159.7KB <= 160KB).
__global__ __launch_bounds__(256, 4) void meganerf_main2(
    const float* __restrict__ x, const float* __restrict__ cent,
    const float* __restrict__ b1, const float* __restrict__ b2,
    const unsigned short* __restrict__ W1T, const unsigned short* __restrict__ W2T,
    float* __restrict__ out) {
  __shared__ unsigned short sH[4 * 2048];    // 16384 B wave-private h
  __shared__ unsigned short sFeat[12 * 512]; // 12288 B block-shared feat frags
  __shared__ float sW[NE][64];               // 2048 B
  __shared__ float sB2[64][4];               // 1024 B
  __shared__ float sB1[NE * NH];             // 8192 B -> total 39936 B

  const int t    = threadIdx.x;
  const int lane = t & 63;
  const int wid  = t >> 6;
  const int l15  = lane & 15;
  const int l4   = lane >> 4;
  const int row0 = blockIdx.x * 64;
  const int gbase = wid * 2048;

  // ---- stage b1 -> LDS (coalesced) ----
#pragma unroll
  for (int j = 0; j < 2; ++j)
    *(f32x4*)&sB1[t * 4 + j * 1024] = *(const f32x4a*)&b1[t * 4 + j * 1024];

  // ---- feat -> LDS: wave wid converts ITS 16 points (no 4x redundancy) ----
  {
    const float* gr = x + (size_t)(row0 + 16 * wid + l15) * 93 + 3;
    f32x4 v0, v1;
    v0 = *(const f32x4a*)(gr + 8 * l4);
    v1 = *(const f32x4a*)(gr + 8 * l4 + 4);
    *(bf16x8*)&sFeat[((0 * 4 + l4) * 64 + 16 * wid + l15) * 8] = cvt8(v0, v1);
    v0 = *(const f32x4a*)(gr + 32 + 8 * l4);
    v1 = *(const f32x4a*)(gr + 36 + 8 * l4);
    *(bf16x8*)&sFeat[((1 * 4 + l4) * 64 + 16 * wid + l15) * 8] = cvt8(v0, v1);
    if (l4 < 3) {
      v0 = *(const f32x4a*)(gr + 64 + 8 * l4);
      v1 = *(const f32x4a*)(gr + 68 + 8 * l4);
    } else {
      f32x2 tl = *(const f32x2a*)(gr + 88);
      v0[0] = tl[0]; v0[1] = tl[1]; v0[2] = 0.f; v0[3] = 0.f;
      v1[0] = 0.f; v1[1] = 0.f; v1[2] = 0.f; v1[3] = 0.f;
    }
    *(bf16x8*)&sFeat[((2 * 4 + l4) * 64 + 16 * wid + l15) * 8] = cvt8(v0, v1);
  }

  // ---- per-point expert weights: each wave handles its 16 points ----
  if (lane < 16) {
    const int pt = 16 * wid + lane;
    const float* gx = x + (size_t)(row0 + pt) * 93;
    float px = gx[0], py = gx[1], pz = gx[2];
    float dist[NE], inv[NE];
    float mind = 3.4e38f;
#pragma unroll
    for (int e = 0; e < NE; ++e) {
      float dx = px - cent[e * 3 + 0];
      float dy = py - cent[e * 3 + 1];
      float dz = pz - cent[e * 3 + 2];
      float d2 = dx * dx + dy * dy + dz * dz;
      float d = sqrtf(fmaxf(d2, 0.f));
      dist[e] = d;
      inv[e] = 1.f / (d + 1e-8f);
      mind = fminf(mind, d);
    }
    float s = 0.f;
#pragma unroll
    for (int e = 0; e < NE; ++e) {
      if (dist[e] > 2.0f * mind) inv[e] = 0.f;
      s += inv[e];
    }
    float rs = 1.f / s;
    float bb[4] = {0.f, 0.f, 0.f, 0.f};
#pragma unroll
    for (int e = 0; e < NE; ++e) {
      float w = inv[e] * rs;
      sW[e][pt] = w;
#pragma unroll
      for (int o = 0; o < 4; ++o) bb[o] += w * b2[e * 4 + o];
    }
#pragma unroll
    for (int o = 0; o < 4; ++o) sB2[pt][o] = bb[o];
  }
  __syncthreads();  // sB1, sFeat, sW, sB2 ready

  // ---- main loop ----
  bf16x8 w1A0, w1A1, w1A2, w1B0, w1B1, w1B2;  // mf0 W1, double-buffered
  bf16x8 w1m1_0, w1m1_1, w1m1_2;              // mf1 W1, single
  bf16x8 bw;                                  // W2 frag, single
  float wv[4];
  f32x4 facc[4] = {{0.f, 0.f, 0.f, 0.f}, {0.f, 0.f, 0.f, 0.f},
                   {0.f, 0.f, 0.f, 0.f}, {0.f, 0.f, 0.f, 0.f}};

  LOADW1MF0(0, 0, w1A0, w1A1, w1A2);

  for (int i = 0; i < 16; i += 2) {
    const int e = i >> 1;
    const int e2 = ((i + 2) & 15) >> 1;
    STEPD(e, 0, 1, e, 1, w1A0, w1A1, w1A2, w1B0, w1B1, w1B2);
    STEPD(e, 1, 0, e2, 0, w1B0, w1B1, w1B2, w1A0, w1A1, w1A2);
  }

  // ---- cross-wave reduction (sOutP aliases sH) ----
  __syncthreads();
  float* sOutP = (float*)sH;
  if (l15 < 4) {
#pragma unroll
    for (int rf = 0; rf < 4; ++rf)
#pragma unroll
      for (int r = 0; r < 4; ++r)
        sOutP[(wid * 64 + 16 * rf + 4 * l4 + r) * 4 + l15] = facc[rf][r];
  }
  __syncthreads();
  {
    const int row = t >> 2, o = t & 3;
    float v = sB2[row][o] + sOutP[(0 * 64 + row) * 4 + o] + sOutP[(1 * 64 + row) * 4 + o] +
              sOutP[(2 * 64 + row) * 4 + o] + sOutP[(3 * 64 + row) * 4 + o];
    out[row0 * 4 + t] = v;
  }
}

extern "C" void kernel_launch(void* const* d_in, const int* in_sizes, int n_in,
                              void* d_out, int out_size, void* d_ws, size_t ws_size,
                              hipStream_t stream) {
  const float* x    = (const float*)d_in[0];
  const float* cent = (const float*)d_in[1];
  const float* W1   = (const float*)d_in[2];
  const float* b1   = (const float*)d_in[3];
  const float* W2   = (const float*)d_in[4];
  const float* b2   = (const float*)d_in[5];
  float* out = (float*)d_out;

  unsigned short* W1T = (unsigned short*)d_ws;   // 393216 B
  unsigned short* W2T = W1T + NE * NH * 96;      // 65536 B

  prep<<<40, 256, 0, stream>>>(W1, W2, W1T, W2T);
  meganerf_main2<<<NPTS / 64, 256, 0, stream>>>(x, cent, b1, b2, W1T, W2T, out);
}

// Round 12
// 163.447 us; speedup vs baseline: 1.1234x; 1.1234x over previous
//
#include <hip/hip_runtime.h>

#define NPTS 131072
#define NE 8
#define DIN 90
#define NH 256

typedef __attribute__((ext_vector_type(8))) short bf16x8;
typedef __attribute__((ext_vector_type(4))) float f32x4;
typedef __attribute__((ext_vector_type(2))) float f32x2;
typedef __attribute__((ext_vector_type(4))) unsigned int u32x4;
typedef __attribute__((ext_vector_type(2))) unsigned int u32x2;
typedef __attribute__((ext_vector_type(4), aligned(4))) float f32x4a;
typedef __attribute__((ext_vector_type(2), aligned(4))) float f32x2a;

// exact RNE scalar (prep only)
__device__ __forceinline__ unsigned short f2bf(float f) {
  unsigned int u = __float_as_uint(f);
  u += 0x7fffu + ((u >> 16) & 1u);
  return (unsigned short)(u >> 16);
}

#if defined(__has_builtin) && __has_builtin(__builtin_amdgcn_cvt_pk_bf16_f32)
typedef __attribute__((ext_vector_type(2))) __bf16 bf16x2;
__device__ __forceinline__ unsigned int pkbf(float f0, float f1) {
  bf16x2 r = __builtin_amdgcn_cvt_pk_bf16_f32(f0, f1);
  return __builtin_bit_cast(unsigned int, r);
}
#else
__device__ __forceinline__ unsigned int pkbf(float f0, float f1) {
  unsigned int u0 = __float_as_uint(f0) + 0x7fffu;
  unsigned int u1 = __float_as_uint(f1) + 0x7fffu;
  return __builtin_amdgcn_perm(u1, u0, 0x07060302u);
}
#endif

__device__ __forceinline__ bf16x8 cvt8(f32x4 a, f32x4 b) {
  u32x4 r;
  r[0] = pkbf(a[0], a[1]);
  r[1] = pkbf(a[2], a[3]);
  r[2] = pkbf(b[0], b[1]);
  r[3] = pkbf(b[2], b[3]);
  return __builtin_bit_cast(bf16x8, r);
}

// Coalesced prep. Blocks 0..31: W1 (e = blk>>2, n0 = (blk&3)*64).
// Blocks 32..39: W2, one expert each.
__global__ __launch_bounds__(256) void prep(const float* __restrict__ W1,
                                            const float* __restrict__ W2,
                                            unsigned short* __restrict__ W1T,
                                            unsigned short* __restrict__ W2T) {
  const int t = threadIdx.x;
  if (blockIdx.x < 32) {
    // W1 [8][90][256] f32 -> W1T[(e*256+n)*96 + kp] bf16, kp>=90 zero-padded
    const int e = blockIdx.x >> 2;
    const int n0 = (blockIdx.x & 3) * 64;
    __shared__ unsigned int ld[64][49];  // stride 49 = 17 mod 32 -> conflict-free
    const int nl = t & 63;
    const int kq = t >> 6;
#pragma unroll
    for (int j = 0; j < 12; ++j) {
      const int kp2 = kq + 4 * j;  // 0..47
      const int k0 = 2 * kp2, k1 = k0 + 1;
      unsigned int lo = 0, hi = 0;
      if (k0 < DIN) lo = f2bf(W1[((size_t)e * DIN + k0) * NH + n0 + nl]);  // coalesced
      if (k1 < DIN) hi = f2bf(W1[((size_t)e * DIN + k1) * NH + n0 + nl]);
      ld[nl][kp2] = lo | (hi << 16);
    }
    __syncthreads();
    unsigned int* dst = (unsigned int*)(W1T + (size_t)(e * NH + n0) * 96);
#pragma unroll
    for (int j = 0; j < 12; ++j) {
      const int u = t + 256 * j;
      dst[u] = ld[u / 48][u % 48];  // 3072 contiguous dwords, fully coalesced
    }
  } else {
    // W2 [8][256][4] f32 -> W2T[(e*16+o)*NH + k] bf16, o>=4 zero-padded
    const int e = blockIdx.x - 32;
    unsigned int* dst = (unsigned int*)W2T + (size_t)e * 2048;  // 16*256 bf16 = 2048 dw
    const float* src = W2 + (size_t)e * 1024;
#pragma unroll
    for (int j = 0; j < 8; ++j) {
      const int u = t + 256 * j;  // 0..2047 dwords, stores coalesced
      const int o = u >> 7;       // 0..15
      const int kp = u & 127;     // k pair
      unsigned int v = 0;
      if (o < 4) {
        unsigned int lo = f2bf(src[(2 * kp) * 4 + o]);
        unsigned int hi = f2bf(src[(2 * kp + 1) * 4 + o]);
        v = lo | (hi << 16);
      }
      dst[u] = v;
    }
  }
}

// Banked best (R9, measured 163.6us total / ~97us main). Structure equilibrium:
// (256,3) -> ~148 unified regs (84 arch + 64 acc) -> 3 waves/SIMD. Measured
// refutations: (256,4) cap spills this structure 3x (R8 demand~158, R17 even
// with feat-in-LDS: VGPR squeezed to 64, WRITE 23.5MB, main 115us); layer-2
// reg-pipelining spills (R6); mfma16 no-LDS-h variant is clean but slower
// (R7: round-trip was latency-hidden); expert sparsity halves MFMA work but
// pre-pipeline cost exceeds the win (R12/R16: 172-173 vs 163.6); cooperative
// mega-kernel spills structurally (R10/R13). setprio: neutral-to-noise here.
__global__ __launch_bounds__(256, 3) void meganerf_main(
    const float* __restrict__ x, const float* __restrict__ cent,
    const float* __restrict__ b1, const float* __restrict__ b2,
    const unsigned short* __restrict__ W1T, const unsigned short* __restrict__ W2T,
    float* __restrict__ out) {
  __shared__ unsigned short sH[4 * 2048];  // 16384 B wave-private h (A-frag order)
  __shared__ float sW[NE][64];             // 2048 B
  __shared__ float sB2[64][4];             // 1024 B
  __shared__ float sB1[NE * NH];           // 8192 B  -> total 27648 B

  const int t    = threadIdx.x;
  const int lane = t & 63;
  const int wid  = t >> 6;
  const int l15  = lane & 15;
  const int l4   = lane >> 4;
  const int row0 = blockIdx.x * 64;
  const int gbase = wid * 2048;

  // ---- stage b1 -> LDS (coalesced) ----
#pragma unroll
  for (int j = 0; j < 2; ++j)
    *(f32x4*)&sB1[t * 4 + j * 1024] = *(const f32x4a*)&b1[t * 4 + j * 1024];

  // ---- feat fragments (MFMA B operand B[k][n=row]), regs for all experts ----
  bf16x8 bfr[4][3];
#pragma unroll
  for (int nf = 0; nf < 4; ++nf) {
    const float* gr = x + (size_t)(row0 + 16 * nf + l15) * 93 + 3;
    f32x4 v0, v1;
    v0 = *(const f32x4a*)(gr + 8 * l4);
    v1 = *(const f32x4a*)(gr + 8 * l4 + 4);
    bfr[nf][0] = cvt8(v0, v1);
    v0 = *(const f32x4a*)(gr + 32 + 8 * l4);
    v1 = *(const f32x4a*)(gr + 36 + 8 * l4);
    bfr[nf][1] = cvt8(v0, v1);
    if (l4 < 3) {
      v0 = *(const f32x4a*)(gr + 64 + 8 * l4);
      v1 = *(const f32x4a*)(gr + 68 + 8 * l4);
    } else {
      f32x2 tl = *(const f32x2a*)(gr + 88);
      v0[0] = tl[0]; v0[1] = tl[1]; v0[2] = 0.f; v0[3] = 0.f;
      v1[0] = 0.f; v1[1] = 0.f; v1[2] = 0.f; v1[3] = 0.f;
    }
    bfr[nf][2] = cvt8(v0, v1);
  }

  // ---- per-point expert weights ----
  if (t < 64) {
    const float* gx = x + (size_t)(row0 + t) * 93;
    float px = gx[0], py = gx[1], pz = gx[2];
    float dist[NE], inv[NE];
    float mind = 3.4e38f;
#pragma unroll
    for (int e = 0; e < NE; ++e) {
      float dx = px - cent[e * 3 + 0];
      float dy = py - cent[e * 3 + 1];
      float dz = pz - cent[e * 3 + 2];
      float d2 = dx * dx + dy * dy + dz * dz;
      float d = sqrtf(fmaxf(d2, 0.f));
      dist[e] = d;
      inv[e] = 1.f / (d + 1e-8f);
      mind = fminf(mind, d);
    }
    float s = 0.f;
#pragma unroll
    for (int e = 0; e < NE; ++e) {
      if (dist[e] > 2.0f * mind) inv[e] = 0.f;
      s += inv[e];
    }
    float rs = 1.f / s;
    float bb[4] = {0.f, 0.f, 0.f, 0.f};
#pragma unroll
    for (int e = 0; e < NE; ++e) {
      float w = inv[e] * rs;
      sW[e][t] = w;
#pragma unroll
      for (int o = 0; o < 4; ++o) bb[o] += w * b2[e * 4 + o];
    }
#pragma unroll
    for (int o = 0; o < 4; ++o) sB2[t][o] = bb[o];
  }
  __syncthreads();   // covers sB1, sW, sB2

  // ---- pipelined (expert, chunk) loop ----
  bf16x8 w1buf[2][6];   // W1T frags, prefetched one chunk ahead
  bf16x8 bwbuf[2];      // W2T frag, prefetched ahead, issued BEFORE w1 group
  float wv[4];

  auto loadW1 = [&](int idx, int buf) {
    const int e = idx >> 1, c = idx & 1;
    const unsigned short* p =
        W1T + (size_t)(e * NH + 128 * c + 32 * wid + l15) * 96 + 8 * l4;
#pragma unroll
    for (int mf = 0; mf < 2; ++mf)
#pragma unroll
      for (int ks = 0; ks < 3; ++ks)
        w1buf[buf][mf * 3 + ks] = *(const bf16x8*)(p + mf * (16 * 96) + 32 * ks);
  };
  auto loadBW = [&](int idx, int buf) {
    const int e = idx >> 1, c = idx & 1;
    bwbuf[buf] = *(const bf16x8*)(W2T + (size_t)(e * 16 + l15) * NH +
                                  128 * c + 32 * wid + 8 * l4);
  };

  loadBW(0, 0);
  loadW1(0, 0);

  f32x4 facc[4] = {{0.f, 0.f, 0.f, 0.f}, {0.f, 0.f, 0.f, 0.f},
                   {0.f, 0.f, 0.f, 0.f}, {0.f, 0.f, 0.f, 0.f}};

#pragma unroll 2
  for (int i = 0; i < 16; ++i) {
    const int e = i >> 1, c = i & 1, cur = i & 1, nxt = cur ^ 1;
    const int colbase = 128 * c + 32 * wid;

    // current-iter LDS operands (issue early; ~120cy latency)
    f32x4 b1v0 = *(const f32x4*)&sB1[e * NH + colbase + 4 * l4];
    f32x4 b1v1 = *(const f32x4*)&sB1[e * NH + colbase + 16 + 4 * l4];
    if (c == 0) {
#pragma unroll
      for (int nf = 0; nf < 4; ++nf) wv[nf] = sW[e][16 * nf + l15];
    }

    // next-iter VMEM prefetch: bw FIRST (vmcnt FIFO), then the 6 W1T frags
    const int ip = (i + 1) & 15;
    loadBW(ip, nxt);
    loadW1(ip, nxt);

    // ---- layer 1, mf-sequential (16 AGPR live) ----
#pragma unroll
    for (int mf = 0; mf < 2; ++mf) {
      const f32x4 b1v = (mf == 0) ? b1v0 : b1v1;
      f32x4 acc[4];
      __builtin_amdgcn_s_setprio(1);   // own the matrix pipe for this cluster
#pragma unroll
      for (int nf = 0; nf < 4; ++nf)
        acc[nf] = __builtin_amdgcn_mfma_f32_16x16x32_bf16(
            w1buf[cur][mf * 3 + 0], bfr[nf][0], b1v, 0, 0, 0);
#pragma unroll
      for (int ks = 1; ks < 3; ++ks)
#pragma unroll
        for (int nf = 0; nf < 4; ++nf)
          acc[nf] = __builtin_amdgcn_mfma_f32_16x16x32_bf16(
              w1buf[cur][mf * 3 + ks], bfr[nf][ks], acc[nf], 0, 0, 0);
      __builtin_amdgcn_s_setprio(0);

      // epilogue: relu*w, pack, wave-private A-frag-order store
#pragma unroll
      for (int nf = 0; nf < 4; ++nf) {
        const float w = wv[nf];
        f32x4 a = acc[nf];
        f32x2 p0, p1;
        p0[0] = a[0]; p0[1] = a[1];
        p1[0] = a[2]; p1[1] = a[3];
        const f32x2 z = {0.f, 0.f};
        p0 = __builtin_elementwise_max(p0, z) * w;
        p1 = __builtin_elementwise_max(p1, z) * w;
        u32x2 pk;
        pk[0] = pkbf(p0[0], p0[1]);
        pk[1] = pkbf(p1[0], p1[1]);
        *(u32x2*)&sH[gbase + (nf * 64 + (l15 + 16 * (2 * mf + (l4 >> 1)))) * 8 +
                     4 * (l4 & 1)] = pk;
      }
    }

    // ---- layer 2 (wave-private; bwbuf[cur] loaded LAST iter -> no vm drain) ----
    __builtin_amdgcn_s_setprio(1);
#pragma unroll
    for (int rf = 0; rf < 4; ++rf) {
      bf16x8 ah = *(const bf16x8*)&sH[gbase + (rf * 64 + lane) * 8];
      facc[rf] = __builtin_amdgcn_mfma_f32_16x16x32_bf16(ah, bwbuf[cur], facc[rf], 0, 0, 0);
    }
    __builtin_amdgcn_s_setprio(0);
  }

  // ---- cross-wave reduction (sOutP aliased onto sH: 4*64*4 f32 = 4 KB) ----
  __syncthreads();
  float* sOutP = (float*)sH;
  if (l15 < 4) {
#pragma unroll
    for (int rf = 0; rf < 4; ++rf)
#pragma unroll
      for (int r = 0; r < 4; ++r)
        sOutP[(wid * 64 + 16 * rf + 4 * l4 + r) * 4 + l15] = facc[rf][r];
  }
  __syncthreads();
  {
    const int row = t >> 2, o = t & 3;
    float v = sB2[row][o] + sOutP[(0 * 64 + row) * 4 + o] + sOutP[(1 * 64 + row) * 4 + o] +
              sOutP[(2 * 64 + row) * 4 + o] + sOutP[(3 * 64 + row) * 4 + o];
    out[row0 * 4 + t] = v;
  }
}

extern "C" void kernel_launch(void* const* d_in, const int* in_sizes, int n_in,
                              void* d_out, int out_size, void* d_ws, size_t ws_size,
                              hipStream_t stream) {
  const float* x    = (const float*)d_in[0];
  const float* cent = (const float*)d_in[1];
  const float* W1   = (const float*)d_in[2];
  const float* b1   = (const float*)d_in[3];
  const float* W2   = (const float*)d_in[4];
  const float* b2   = (const float*)d_in[5];
  float* out = (float*)d_out;

  unsigned short* W1T = (unsigned short*)d_ws;   // 393216 B
  unsigned short* W2T = W1T + NE * NH * 96;      // 65536 B

  prep<<<40, 256, 0, stream>>>(W1, W2, W1T, W2T);
  meganerf_main<<<NPTS / 64, 256, 0, stream>>>(x, cent, b1, b2, W1T, W2T, out);
}